// Round 1
// baseline (22411.624 us; speedup 1.0000x reference)
//
#include <hip/hip_runtime.h>
#include <hip/hip_bf16.h>
#include <stdint.h>

// LSTM: T=2048, B=64, I=256, H=256, gates 4H=1024, K = I+H = 512.
// 64 WGs x 256 threads. WG w owns h-cols [4w,4w+4) -> gate rows {256*g + 4w + jj}.
// Weight fragments resident in VGPRs. Flag-synced step loop, double-buffered h.

#define T_STEPS 2048
#define NWG 64

typedef float f32x4 __attribute__((ext_vector_type(4)));
typedef short bf16x8 __attribute__((ext_vector_type(8)));
typedef uint32_t u32x4 __attribute__((ext_vector_type(4)));

__device__ __forceinline__ short tobf(float f) {
    __hip_bfloat16 h = __float2bfloat16(f);
    return *reinterpret_cast<short*>(&h);
}

__device__ __forceinline__ bf16x8 pack8(f32x4 a, f32x4 b) {
    bf16x8 r;
    r[0] = tobf(a[0]); r[1] = tobf(a[1]); r[2] = tobf(a[2]); r[3] = tobf(a[3]);
    r[4] = tobf(b[0]); r[5] = tobf(b[1]); r[6] = tobf(b[2]); r[7] = tobf(b[3]);
    return r;
}

__device__ __forceinline__ bf16x8 frag4(uint32_t a, uint32_t b, uint32_t c, uint32_t d) {
    u32x4 t; t.x = a; t.y = b; t.z = c; t.w = d;
    return __builtin_bit_cast(bf16x8, t);
}

__device__ __forceinline__ float fast_sig(float x) {
    float e = __builtin_amdgcn_exp2f(-1.4426950408889634f * x);
    return __builtin_amdgcn_rcpf(1.0f + e);
}
__device__ __forceinline__ float fast_tanh(float x) {
    float xc = fminf(fmaxf(x, -15.0f), 15.0f);
    float e = __builtin_amdgcn_exp2f(2.8853900817779268f * xc);
    return (e - 1.0f) * __builtin_amdgcn_rcpf(e + 1.0f);
}

__global__ __launch_bounds__(256, 1)
void lstm_fused(const float* __restrict__ x,
                const float* __restrict__ W_ih,
                const float* __restrict__ W_hh,
                const float* __restrict__ b_ih,
                const float* __restrict__ b_hh,
                float* __restrict__ out,
                uint32_t* __restrict__ hbuf,   // 2 x [64][128] u32 (bf16 pairs)
                uint32_t* __restrict__ flags)  // NWG counters, stride 16 u32
{
    const int wg   = blockIdx.x;     // 0..63
    const int tid  = threadIdx.x;    // 0..255
    const int wv   = tid >> 6;       // wave 0..3 (M-tile = batches 16*wv..16*wv+15)
    const int l    = tid & 63;
    const int l15  = l & 15;
    const int lk   = l >> 4;         // 0..3
    const int gate = l15 >> 2;       // 0:i 1:f 2:g 3:o
    const int jj   = l15 & 3;        // h-col within WG slice
    const int grow = 256 * gate + 4 * wg + jj;   // gate row in [0,1024)

    // ---- resident weight fragments: B[k][n] = Wcat[grow(n)][k], 16 ktiles of K=32 ----
    bf16x8 wfrag[16];
#pragma unroll
    for (int kt = 0; kt < 16; ++kt) {
        const float* src = (kt < 8)
            ? (W_ih + (size_t)grow * 256 + kt * 32 + lk * 8)
            : (W_hh + (size_t)grow * 256 + (kt - 8) * 32 + lk * 8);
        f32x4 a = *(const f32x4*)(src);
        f32x4 b = *(const f32x4*)(src + 4);
        wfrag[kt] = pack8(a, b);
    }
    const float bias = b_ih[grow] + b_hh[grow];

    const int arow = 16 * wv + l15;            // A-fragment row (batch)
    const float* xbase = x + (size_t)arow * 256 + lk * 8;

    float cst[4] = {0.f, 0.f, 0.f, 0.f};      // cell state, rows 16*wv+4*lk+r

    // ---- stage x_0 into registers ----
    f32x4 xs[16];
#pragma unroll
    for (int kt = 0; kt < 8; ++kt) {
        const float* p = xbase + kt * 32;
        xs[2 * kt]     = *(const f32x4*)(p);
        xs[2 * kt + 1] = *(const f32x4*)(p + 4);
    }

    for (int s = 0; s < T_STEPS; ++s) {
        // convert staged x_s to A fragments
        bf16x8 af[8];
#pragma unroll
        for (int kt = 0; kt < 8; ++kt) af[kt] = pack8(xs[2 * kt], xs[2 * kt + 1]);

        f32x4 acc0 = {0.f, 0.f, 0.f, 0.f};
        f32x4 acc1 = {0.f, 0.f, 0.f, 0.f};
        // x-half MFMAs (independent of h_{s-1}; two chains for ILP)
#pragma unroll
        for (int kt = 0; kt < 8; kt += 2) {
            acc0 = __builtin_amdgcn_mfma_f32_16x16x32_bf16(af[kt],     wfrag[kt],     acc0, 0, 0, 0);
            acc1 = __builtin_amdgcn_mfma_f32_16x16x32_bf16(af[kt + 1], wfrag[kt + 1], acc1, 0, 0, 0);
        }

        // ---- wait for h_s (producers have finished step s-1) ----
        if (s > 0) {
            const uint32_t target = 4u * (uint32_t)s;
            const uint32_t* fp = flags + l * 16;
            while (true) {
                uint32_t v = __hip_atomic_load(fp, __ATOMIC_RELAXED, __HIP_MEMORY_SCOPE_AGENT);
                if (__all((int)(v >= target))) break;
                __builtin_amdgcn_s_sleep(1);
            }
            __builtin_amdgcn_fence(__ATOMIC_ACQUIRE, "agent");
        }

        // ---- load h_s fragments (agent-scope coherent) ----
        const uint32_t* hb = hbuf + (size_t)(s & 1) * 8192 + (size_t)arow * 128 + 4 * lk;
        uint32_t hw[32];
#pragma unroll
        for (int kh = 0; kh < 8; ++kh) {
#pragma unroll
            for (int i = 0; i < 4; ++i)
                hw[kh * 4 + i] = __hip_atomic_load(hb + kh * 16 + i,
                                                   __ATOMIC_RELAXED, __HIP_MEMORY_SCOPE_AGENT);
        }

        // ---- prefetch x_{s+1} while h loads are in flight ----
        if (s + 1 < T_STEPS) {
            const float* xp = xbase + (size_t)(s + 1) * 16384;
#pragma unroll
            for (int kt = 0; kt < 8; ++kt) {
                xs[2 * kt]     = *(const f32x4*)(xp + kt * 32);
                xs[2 * kt + 1] = *(const f32x4*)(xp + kt * 32 + 4);
            }
        }

        bf16x8 hf[8];
#pragma unroll
        for (int kh = 0; kh < 8; ++kh)
            hf[kh] = frag4(hw[4 * kh], hw[4 * kh + 1], hw[4 * kh + 2], hw[4 * kh + 3]);

#pragma unroll
        for (int kh = 0; kh < 8; kh += 2) {
            acc0 = __builtin_amdgcn_mfma_f32_16x16x32_bf16(hf[kh],     wfrag[8 + kh],     acc0, 0, 0, 0);
            acc1 = __builtin_amdgcn_mfma_f32_16x16x32_bf16(hf[kh + 1], wfrag[8 + kh + 1], acc1, 0, 0, 0);
        }

        // ---- epilogue: gather i/f/g/o across lane groups, update c, h ----
        uint32_t* hw_out = hbuf + (size_t)((s + 1) & 1) * 8192;
        const int orow0 = 16 * wv + 4 * lk;    // D row base (batch)
        float hv[4];
#pragma unroll
        for (int r = 0; r < 4; ++r) {
            float vo  = acc0[r] + acc1[r] + bias;
            float v4  = __shfl_xor(vo, 4);
            float v8  = __shfl_xor(vo, 8);
            float v12 = __shfl_xor(vo, 12);
            // value of gate g' lives in: vo if g'==gate, v4 if g'==gate^1, v8 if g'==gate^2, v12 if g'==gate^3
            float iv = (gate == 0) ? vo : ((gate == 1) ? v4 : ((gate == 2) ? v8 : v12));
            float fv = (gate == 1) ? vo : ((gate == 0) ? v4 : ((gate == 3) ? v8 : v12));
            float gv = (gate == 2) ? vo : ((gate == 3) ? v4 : ((gate == 0) ? v8 : v12));
            float ov = (gate == 3) ? vo : ((gate == 2) ? v4 : ((gate == 1) ? v8 : v12));
            float cn = fast_sig(fv) * cst[r] + fast_sig(iv) * fast_tanh(gv);
            cst[r] = cn;
            hv[r] = fast_sig(ov) * fast_tanh(cn);
        }

        // ---- pack pairs (jj, jj^1) and store h slice as bf16 (agent-scope) ----
#pragma unroll
        for (int r = 0; r < 4; ++r) {
            uint32_t hu = (uint32_t)(uint16_t)tobf(hv[r]);
            uint32_t pu = (uint32_t)__shfl_xor((int)hu, 1);
            uint32_t packed = hu | (pu << 16);
            if ((l & 13) == 0) {   // one lane per (row-group, even jj), dedup l^4/l^8/l^12
                __hip_atomic_store(hw_out + (size_t)(orow0 + r) * 128 + 2 * wg + (jj >> 1),
                                   packed, __ATOMIC_RELAXED, __HIP_MEMORY_SCOPE_AGENT);
            }
        }

        if (s == T_STEPS - 1) {
#pragma unroll
            for (int r = 0; r < 4; ++r)
                if ((l & 12) == 0)
                    out[(size_t)(orow0 + r) * 256 + 4 * wg + jj] = hv[r];
        }

        // ---- release: one RMW per wave; waitcnt covers the wave's h stores ----
        if (l == 0)
            __hip_atomic_fetch_add(flags + wg * 16, 1u,
                                   __ATOMIC_RELEASE, __HIP_MEMORY_SCOPE_AGENT);
    }
}

extern "C" void kernel_launch(void* const* d_in, const int* in_sizes, int n_in,
                              void* d_out, int out_size, void* d_ws, size_t ws_size,
                              hipStream_t stream) {
    const float* x    = (const float*)d_in[0];
    const float* W_ih = (const float*)d_in[1];
    const float* W_hh = (const float*)d_in[2];
    const float* b_ih = (const float*)d_in[3];
    const float* b_hh = (const float*)d_in[4];
    float* out = (float*)d_out;

    uint32_t* hbuf  = (uint32_t*)d_ws;          // 2 * 8192 u32
    uint32_t* flags = hbuf + 2 * 8192;          // 64 * 16 u32

    // zero h_0 (both buffers) + flags each call (graph-capture safe)
    hipMemsetAsync(d_ws, 0, (2 * 8192 + NWG * 16) * sizeof(uint32_t), stream);

    lstm_fused<<<dim3(NWG), dim3(256), 0, stream>>>(x, W_ih, W_hh, b_ih, b_hh,
                                                    out, hbuf, flags);
}

// Round 3
// 12866.841 us; speedup vs baseline: 1.7418x; 1.7418x over previous
//
#include <hip/hip_runtime.h>
#include <hip/hip_bf16.h>
#include <stdint.h>

// LSTM: T=2048, B=64, I=256, H=256, gates 4H=1024, K = I+H = 512.
// 32 WGs x 256 threads. WG w owns h-cols [8w,8w+8) -> 32 gate rows
// (2 fragment groups p=0,1). Weights resident in VGPRs (128/lane).
// Flag-synced step loop, double-buffered h in L3-coherent scratch.
// Sync design: one release-store per WG per step, one polling wave per WG.

#define T_STEPS 2048
#define NWG 32

typedef float f32x4 __attribute__((ext_vector_type(4)));
typedef short bf16x8 __attribute__((ext_vector_type(8)));
typedef uint32_t u32x4 __attribute__((ext_vector_type(4)));

__device__ __forceinline__ short tobf(float f) {
    __hip_bfloat16 h = __float2bfloat16(f);
    return *reinterpret_cast<short*>(&h);
}

__device__ __forceinline__ bf16x8 pack8(f32x4 a, f32x4 b) {
    bf16x8 r;
    r[0] = tobf(a[0]); r[1] = tobf(a[1]); r[2] = tobf(a[2]); r[3] = tobf(a[3]);
    r[4] = tobf(b[0]); r[5] = tobf(b[1]); r[6] = tobf(b[2]); r[7] = tobf(b[3]);
    return r;
}

__device__ __forceinline__ bf16x8 frag_u64(unsigned long long a, unsigned long long b) {
    u32x4 t;
    t.x = (uint32_t)a; t.y = (uint32_t)(a >> 32);
    t.z = (uint32_t)b; t.w = (uint32_t)(b >> 32);
    return __builtin_bit_cast(bf16x8, t);
}

__device__ __forceinline__ float fast_sig(float x) {
    float e = __builtin_amdgcn_exp2f(-1.4426950408889634f * x);
    return __builtin_amdgcn_rcpf(1.0f + e);
}
__device__ __forceinline__ float fast_tanh(float x) {
    float xc = fminf(fmaxf(x, -15.0f), 15.0f);
    float e = __builtin_amdgcn_exp2f(2.8853900817779268f * xc);
    return (e - 1.0f) * __builtin_amdgcn_rcpf(e + 1.0f);
}

__global__ __launch_bounds__(256, 1)
void lstm_fused(const float* __restrict__ x,
                const float* __restrict__ W_ih,
                const float* __restrict__ W_hh,
                const float* __restrict__ b_ih,
                const float* __restrict__ b_hh,
                float* __restrict__ out,
                uint32_t* __restrict__ hbuf,   // 2 x [64][128] u32 (bf16 pairs)
                uint32_t* __restrict__ flags)  // NWG counters, stride 16 u32
{
    const int wg   = blockIdx.x;     // 0..31
    const int tid  = threadIdx.x;    // 0..255
    const int wv   = tid >> 6;       // wave 0..3 = batch group (rows 16*wv..+16)
    const int l    = tid & 63;
    const int l15  = l & 15;
    const int lk   = l >> 4;         // 0..3
    const int gate = l15 >> 2;       // 0:i 1:f 2:g 3:o
    const int jj   = l15 & 3;

    // ---- resident weight fragments: 2 N-groups x 16 ktiles of K=32 ----
    bf16x8 wf[2][16];
    float bias[2];
#pragma unroll
    for (int p = 0; p < 2; ++p) {
        const int grow = 256 * gate + 8 * wg + 4 * p + jj;   // gate row
#pragma unroll
        for (int kt = 0; kt < 16; ++kt) {
            const float* src = (kt < 8)
                ? (W_ih + (size_t)grow * 256 + kt * 32 + lk * 8)
                : (W_hh + (size_t)grow * 256 + (kt - 8) * 32 + lk * 8);
            wf[p][kt] = pack8(*(const f32x4*)(src), *(const f32x4*)(src + 4));
        }
        bias[p] = b_ih[grow] + b_hh[grow];
    }

    const int arow = 16 * wv + l15;            // A-fragment row (batch)
    const float* xbase = x + (size_t)arow * 256 + lk * 8;

    float cst[2][4] = {{0.f,0.f,0.f,0.f},{0.f,0.f,0.f,0.f}};

    // ---- stage x_0 ----
    f32x4 xs[16];
#pragma unroll
    for (int kt = 0; kt < 8; ++kt) {
        xs[2 * kt]     = *(const f32x4*)(xbase + kt * 32);
        xs[2 * kt + 1] = *(const f32x4*)(xbase + kt * 32 + 4);
    }

    for (int s = 0; s < T_STEPS; ++s) {
        // ---- wave 0 polls all WG flags; other waves wait at the barrier ----
        if (s > 0 && tid < 64) {
            const uint32_t target = (uint32_t)s;
            const uint32_t* fp = flags + (l & (NWG - 1)) * 16;
            while (true) {
                uint32_t v = __hip_atomic_load(fp, __ATOMIC_RELAXED, __HIP_MEMORY_SCOPE_AGENT);
                if (__all((int)(v >= target))) break;
                __builtin_amdgcn_s_sleep(1);
            }
        }
        __syncthreads();
        asm volatile("" ::: "memory");   // compiler ordering only; sc1 loads are HW-coherent

        // ---- issue h_s loads first (L3 round trip hides the x-half work) ----
        const unsigned long long* hb = (const unsigned long long*)
            (hbuf + (size_t)(s & 1) * 8192 + (size_t)arow * 128 + 4 * lk);
        unsigned long long hq[16];
#pragma unroll
        for (int kh = 0; kh < 8; ++kh) {
            hq[2 * kh]     = __hip_atomic_load(hb + (size_t)kh * 8,
                                               __ATOMIC_RELAXED, __HIP_MEMORY_SCOPE_AGENT);
            hq[2 * kh + 1] = __hip_atomic_load(hb + (size_t)kh * 8 + 1,
                                               __ATOMIC_RELAXED, __HIP_MEMORY_SCOPE_AGENT);
        }

        // ---- x-half MFMAs (independent of h_s) under the h-load shadow ----
        bf16x8 af[8];
#pragma unroll
        for (int kt = 0; kt < 8; ++kt) af[kt] = pack8(xs[2 * kt], xs[2 * kt + 1]);

        f32x4 aA[2] = {{0.f,0.f,0.f,0.f},{0.f,0.f,0.f,0.f}};
        f32x4 aB[2] = {{0.f,0.f,0.f,0.f},{0.f,0.f,0.f,0.f}};
#pragma unroll
        for (int kt = 0; kt < 8; kt += 2) {
#pragma unroll
            for (int p = 0; p < 2; ++p) {
                aA[p] = __builtin_amdgcn_mfma_f32_16x16x32_bf16(af[kt],     wf[p][kt],     aA[p], 0, 0, 0);
                aB[p] = __builtin_amdgcn_mfma_f32_16x16x32_bf16(af[kt + 1], wf[p][kt + 1], aB[p], 0, 0, 0);
            }
        }

        // ---- prefetch x_{s+1} (plain cached loads; consumed next step) ----
        if (s + 1 < T_STEPS) {
            const float* xp = xbase + (size_t)(s + 1) * 16384;
#pragma unroll
            for (int kt = 0; kt < 8; ++kt) {
                xs[2 * kt]     = *(const f32x4*)(xp + kt * 32);
                xs[2 * kt + 1] = *(const f32x4*)(xp + kt * 32 + 4);
            }
        }

        // ---- h-half MFMAs ----
#pragma unroll
        for (int kh = 0; kh < 8; kh += 2) {
            bf16x8 h0 = frag_u64(hq[2 * kh],     hq[2 * kh + 1]);
            bf16x8 h1 = frag_u64(hq[2 * kh + 2], hq[2 * kh + 3]);
#pragma unroll
            for (int p = 0; p < 2; ++p) {
                aA[p] = __builtin_amdgcn_mfma_f32_16x16x32_bf16(h0, wf[p][8 + kh],     aA[p], 0, 0, 0);
                aB[p] = __builtin_amdgcn_mfma_f32_16x16x32_bf16(h1, wf[p][8 + kh + 1], aB[p], 0, 0, 0);
            }
        }

        // ---- epilogue: gather i/f/g/o across lane groups, update c, h ----
        uint32_t* hw_out = hbuf + (size_t)((s + 1) & 1) * 8192;
        const int orow0 = 16 * wv + 4 * lk;
        float hv[2][4];
#pragma unroll
        for (int p = 0; p < 2; ++p) {
#pragma unroll
            for (int r = 0; r < 4; ++r) {
                float vo  = aA[p][r] + aB[p][r] + bias[p];
                float v4  = __shfl_xor(vo, 4);
                float v8  = __shfl_xor(vo, 8);
                float v12 = __shfl_xor(vo, 12);
                float iv = (gate == 0) ? vo : ((gate == 1) ? v4 : ((gate == 2) ? v8 : v12));
                float fv = (gate == 1) ? vo : ((gate == 0) ? v4 : ((gate == 3) ? v8 : v12));
                float gv = (gate == 2) ? vo : ((gate == 3) ? v4 : ((gate == 0) ? v8 : v12));
                float ov = (gate == 3) ? vo : ((gate == 2) ? v4 : ((gate == 1) ? v8 : v12));
                float cn = fast_sig(fv) * cst[p][r] + fast_sig(iv) * fast_tanh(gv);
                cst[p][r] = cn;
                hv[p][r] = fast_sig(ov) * fast_tanh(cn);
            }
        }

        // ---- store h slice as packed bf16 pairs (sc1, write-through) ----
#pragma unroll
        for (int p = 0; p < 2; ++p) {
#pragma unroll
            for (int r = 0; r < 4; ++r) {
                uint32_t hu = (uint32_t)(uint16_t)tobf(hv[p][r]);
                uint32_t pu = (uint32_t)__shfl_xor((int)hu, 1);
                uint32_t packed = hu | (pu << 16);
                if ((l & 13) == 0) {   // gate==0, jj even; lk free
                    __hip_atomic_store(hw_out + (size_t)(orow0 + r) * 128
                                           + 4 * wg + 2 * p + (jj >> 1),
                                       packed, __ATOMIC_RELAXED, __HIP_MEMORY_SCOPE_AGENT);
                }
            }
        }

        if (s == T_STEPS - 1) {
#pragma unroll
            for (int p = 0; p < 2; ++p)
#pragma unroll
                for (int r = 0; r < 4; ++r)
                    if ((l & 12) == 0)
                        out[(size_t)(orow0 + r) * 256 + 8 * wg + 4 * p + jj] = hv[p][r];
        }

        // ---- drain all waves' stores, then single release-store of the flag ----
        __syncthreads();
        if (tid == 0)
            __hip_atomic_store(flags + wg * 16, (uint32_t)(s + 1),
                               __ATOMIC_RELEASE, __HIP_MEMORY_SCOPE_AGENT);
    }
}

extern "C" void kernel_launch(void* const* d_in, const int* in_sizes, int n_in,
                              void* d_out, int out_size, void* d_ws, size_t ws_size,
                              hipStream_t stream) {
    const float* x    = (const float*)d_in[0];
    const float* W_ih = (const float*)d_in[1];
    const float* W_hh = (const float*)d_in[2];
    const float* b_ih = (const float*)d_in[3];
    const float* b_hh = (const float*)d_in[4];
    float* out = (float*)d_out;

    uint32_t* hbuf  = (uint32_t*)d_ws;          // 2 * 8192 u32
    uint32_t* flags = hbuf + 2 * 8192;          // NWG * 16 u32

    hipMemsetAsync(d_ws, 0, (2 * 8192 + NWG * 16) * sizeof(uint32_t), stream);

    lstm_fused<<<dim3(NWG), dim3(256), 0, stream>>>(x, W_ih, W_hh, b_ih, b_hh,
                                                    out, hbuf, flags);
}